// Round 1
// 155.712 us; speedup vs baseline: 1.0352x; 1.0352x over previous
//
#include <hip/hip_runtime.h>
#include <hip/hip_bf16.h>

// TriplesDistances: B=16, N=512, A=1024
// positions: float32 [B,N,3]; neighbors_j/k: int32 [B,N,A]; out: float32,
// (r_ij | r_ik | r_jk) each [B,N,A] concatenated flat.
//
// R6 post-mortem: top-5 dispatches are all poison fills (~60us @ 6.6 TB/s);
// kernel itself <59us (~50us per R5 decomposition) vs 27us traffic roofline.
// Latency-bound theory: __launch_bounds__(256,8) capped VGPRs at 64, so the
// 8 iv4 index loads (32 regs) + outputs + gathers could not all stay in
// flight -> compiler serialized vmcnt waits, each chunk pays ~full HBM
// latency.
// R7: relax to (256,4) (128 VGPRs, still 16 waves/CU), explicitly two-phase:
//   phase 1 issues ALL 8 global index loads (MLP=8/thread),
//   phase 2 per chunk batches all 8 ds_read_b128 gathers, then computes,
//   then stores. All array indices compile-time constant (full unroll) so
//   everything stays in registers.

namespace {
constexpr int kB = 16;
constexpr int kN = 512;
constexpr int kA = 1024;
constexpr long long kBNA = (long long)kB * kN * kA;  // 8,388,608

typedef int   iv4 __attribute__((ext_vector_type(4)));
typedef float fv4 __attribute__((ext_vector_type(4)));
}  // namespace

__global__ __launch_bounds__(256, 4) void TriplesDistances_kernel(
    const float* __restrict__ pos,   // f32 [B*N*3]
    const int* __restrict__ nj,      // int32 [B*N*A]
    const int* __restrict__ nk,      // int32 [B*N*A]
    float* __restrict__ out)         // f32 [3*B*N*A]
{
    __shared__ fv4 spos[kN];  // 8 KB, float4-padded positions of this batch

    const int bid = blockIdx.x;        // 0..2047
    const int b   = bid >> 7;          // batch (128 blocks per batch)
    const int n0  = (bid & 127) << 2;  // first of 4 rows
    const int tid = threadIdx.x;

    // Stage batch-b positions: 1536 packed floats -> padded float4 layout.
    {
        const float* p = pos + (size_t)b * (kN * 3);
#pragma unroll
        for (int t = 0; t < 6; ++t) {
            const int e = tid + t * 256;
            const int a = e / 3;         // magic-mul, no HW div
            const int c = e - a * 3;
            ((float*)&spos[a])[c] = p[e];
        }
    }

    const int wave = tid >> 6;          // 0..3 -> row n0+wave
    const int lane = tid & 63;
    const int row  = n0 + wave;

    // Wave owns the full 1024-element row; 4 chunks of 256 elements.
    // Thread offset lane*4 => every iv4 load / fv4 store is 1 KB coalesced.
    const long long rowbase = ((long long)b * kN + row) * kA;

    // ---- Phase 1: issue all 8 index loads; keep them ALL in flight. ----
    iv4 j4[4], k4[4];
#pragma unroll
    for (int c = 0; c < 4; ++c) {
        const long long off = rowbase + c * 256 + lane * 4;
        j4[c] = *(const iv4*)(nj + off);
        k4[c] = *(const iv4*)(nk + off);
    }

    __syncthreads();                    // spos ready (placed after load issue)
    const fv4 pi = spos[row];
    const float xi = pi.x, yi = pi.y, zi = pi.z;

    // ---- Phase 2: per chunk, batch gathers -> compute -> store. ----
#pragma unroll
    for (int c = 0; c < 4; ++c) {
        const long long off = rowbase + c * 256 + lane * 4;

        const int js[4] = {j4[c].x, j4[c].y, j4[c].z, j4[c].w};
        const int ks[4] = {k4[c].x, k4[c].y, k4[c].z, k4[c].w};

        // Batch all 8 ds_read_b128 gathers before any compute.
        fv4 pj[4], pk[4];
#pragma unroll
        for (int t = 0; t < 4; ++t) {
            pj[t] = spos[js[t]];
            pk[t] = spos[ks[t]];
        }

        fv4 vij, vik, vjk;
        float* rij = (float*)&vij;
        float* rik = (float*)&vik;
        float* rjk = (float*)&vjk;
#pragma unroll
        for (int t = 0; t < 4; ++t) {
            // safe_norm: sqrtf(0)=0 matches where(s>0, sqrt(s), 0)
            float dx = pj[t].x - xi, dy = pj[t].y - yi, dz = pj[t].z - zi;
            rij[t] = sqrtf(dx * dx + dy * dy + dz * dz);

            dx = pk[t].x - xi; dy = pk[t].y - yi; dz = pk[t].z - zi;
            rik[t] = sqrtf(dx * dx + dy * dy + dz * dz);

            dx = pj[t].x - pk[t].x; dy = pj[t].y - pk[t].y; dz = pj[t].z - pk[t].z;
            rjk[t] = sqrtf(dx * dx + dy * dy + dz * dz);
        }

        // 1 KB coalesced plain stores (overwrite poison-dirty L2 lines).
        *(fv4*)(out + off)            = vij;
        *(fv4*)(out + kBNA + off)     = vik;
        *(fv4*)(out + 2 * kBNA + off) = vjk;
    }
}

extern "C" void kernel_launch(void* const* d_in, const int* in_sizes, int n_in,
                              void* d_out, int out_size, void* d_ws, size_t ws_size,
                              hipStream_t stream) {
    const float* pos = (const float*)d_in[0];
    const int* nj = (const int*)d_in[1];
    const int* nk = (const int*)d_in[2];
    float* out = (float*)d_out;

    // 4 rows per block (1 per wave): grid = B * N/4 = 2048 blocks, 256 threads.
    TriplesDistances_kernel<<<kB * (kN / 4), 256, 0, stream>>>(pos, nj, nk, out);
}